// Round 5
// baseline (466.478 us; speedup 1.0000x reference)
//
#include <hip/hip_runtime.h>

typedef unsigned short ushort_t;
typedef __attribute__((ext_vector_type(4))) float f32x4;
typedef __attribute__((ext_vector_type(8))) short s16x8;
typedef __attribute__((ext_vector_type(8))) unsigned short u16x8;

#define NNODE 2592
#define MATSZ (512*512)
#define INV53 (1.0f/(53.0f + 1e-8f))

__device__ __forceinline__ ushort_t f2b(float f){
  union {unsigned int i; float f;} x; x.f = f;
  unsigned int r = (x.i + 0x7fffu + ((x.i>>16)&1u))>>16;
  return (ushort_t)r;
}

// ---------------------------------------------------------------------------
// prep: 1024 transpose-tile jobs fp32 [k][n] -> bf16 WT[w][n][k].
// Slots 12..15 = (Wself - INV53*W1)  (removes per-layer H1 GEMM).
// Block 0 inits acc/counter.
// ---------------------------------------------------------------------------
__global__ __launch_bounds__(256) void prep_kernel(
    const float* __restrict__ fc1, const float* __restrict__ hc,
    const float* __restrict__ m0, const float* __restrict__ m1,
    const float* __restrict__ ms, ushort_t* __restrict__ WT,
    float* __restrict__ acc, unsigned int* __restrict__ counter)
{
  if (blockIdx.x==0 && threadIdx.x==0){ *acc = 0.f; *counter = 0u; }
  __shared__ float tile[64][65];
  int w = blockIdx.x>>6, t = blockIdx.x&63, bx = t>>3, by = t&7;
  const float* src = (w==0) ? fc1
                   : (w<4)  ? hc + (size_t)(w-1)*MATSZ
                   : (w<8)  ? m0 + (size_t)(w-4)*MATSZ
                   : (w<12) ? m1 + (size_t)(w-8)*MATSZ
                            : ms + (size_t)(w-12)*MATSZ;
  const float* src2 = (w>=12) ? m1 + (size_t)(w-12)*MATSZ : nullptr;
  ushort_t* dst = WT + (size_t)w*MATSZ;
  int r0 = bx*64, c0 = by*64;
  #pragma unroll
  for (int j=0;j<16;j++){
    int idx = j*256 + threadIdx.x;
    int r = idx>>6, c = idx&63;
    size_t off = (size_t)(r0+r)*512 + c0 + c;
    float v = src[off];
    if (w>=12) v -= INV53 * src2[off];
    tile[r][c] = v;
  }
  __syncthreads();
  #pragma unroll
  for (int j=0;j<16;j++){
    int idx = j*256 + threadIdx.x;
    int r = idx>>6, c = idx&63;
    dst[(size_t)(c0+r)*512 + r0 + c] = f2b(tile[c][r]);
  }
}

// ---------------------------------------------------------------------------
// gemm32: 32-row x 128-col tile, barrier-free K-loop.
// A staged in swizzled LDS (32x512 bf16); B streamed global->reg from
// pre-transposed WT[n][k].  4 waves; wave owns 32 cols; acc[2mf][2nf].
// C/D mapping (verified): row = mf*16 + quad*4 + r, col = wave*32+nf*16+ml.
// ---------------------------------------------------------------------------
__device__ __forceinline__ void gemm32(const ushort_t* As,
    const ushort_t* W, int col0, f32x4 acc[2][2])
{
  const int tid = threadIdx.x;
  const int wave = tid>>6, lane = tid&63;
  const int ml = lane&15, quad = lane>>4;
  #pragma unroll
  for (int mf=0;mf<2;mf++)
    #pragma unroll
    for (int nf=0;nf<2;nf++) acc[mf][nf] = (f32x4){0.f,0.f,0.f,0.f};

  const ushort_t* bw0 = W + (size_t)(col0 + wave*32 + ml)*512 + quad*8;
  const ushort_t* bw1 = bw0 + (size_t)16*512;
  const int rsw = ml&7;
  #pragma unroll
  for (int ks=0; ks<16; ks++){
    const int chunk = ks*4 + quad;
    const int abase = (chunk>>3)*64 + (((chunk&7) ^ rsw)<<3);
    s16x8 a0 = *(const s16x8*)&As[(size_t)ml*512 + abase];
    s16x8 a1 = *(const s16x8*)&As[(size_t)(16+ml)*512 + abase];
    s16x8 b0 = *(const s16x8*)(bw0 + ks*32);
    s16x8 b1 = *(const s16x8*)(bw1 + ks*32);
    acc[0][0] = __builtin_amdgcn_mfma_f32_16x16x32_bf16(a0,b0,acc[0][0],0,0,0);
    acc[0][1] = __builtin_amdgcn_mfma_f32_16x16x32_bf16(a0,b1,acc[0][1],0,0,0);
    acc[1][0] = __builtin_amdgcn_mfma_f32_16x16x32_bf16(a1,b0,acc[1][0],0,0,0);
    acc[1][1] = __builtin_amdgcn_mfma_f32_16x16x32_bf16(a1,b1,acc[1][1],0,0,0);
  }
}

// ---------------------------------------------------------------------------
// fc1: X1 = feats @ fc1_W + b.  grid 324 (81 row-tiles x 4 col-tiles).
// ---------------------------------------------------------------------------
__global__ __launch_bounds__(256) void fc1_kernel(
    const float* __restrict__ A_in, const float* __restrict__ V_in,
    const float* __restrict__ L_in, const float* __restrict__ qmask,
    const float* __restrict__ spk, const ushort_t* __restrict__ WT,
    const float* __restrict__ fc1_b, float* __restrict__ X1)
{
  __shared__ __align__(16) ushort_t As[32*512];
  const int b = blockIdx.x, tid = threadIdx.x;
  const int r0 = (b>>2)*32, col0 = (b&3)*128;
  {
    int row = tid>>3, seg = tid&7, gr = r0+row;
    int d = gr/162, rm = gr-d*162, m = rm/54, i = rm-m*54, t = d*54+i;
    const float* pa = ((m==0)?L_in:(m==1)?A_in:V_in) + (size_t)t*512 + seg*64;
    const float* pb = pa;
    bool hassp = (m==0);
    if (hassp){
      int sp = qmask[(i*16+d)*2+1] > qmask[(i*16+d)*2];
      pb = spk + sp*512 + seg*64;
    }
    int rsw = row&7;
    ushort_t* dstA = &As[row*512 + seg*64];
    #pragma unroll
    for (int j=0;j<8;j++){
      f32x4 xa = *(const f32x4*)(pa+j*8), xb = *(const f32x4*)(pa+j*8+4);
      if (hassp){
        f32x4 ya = *(const f32x4*)(pb+j*8), yb = *(const f32x4*)(pb+j*8+4);
        #pragma unroll
        for (int jj=0;jj<4;jj++){ xa[jj]+=ya[jj]; xb[jj]+=yb[jj]; }
      }
      u16x8 v;
      #pragma unroll
      for (int jj=0;jj<4;jj++){ v[jj]=f2b(xa[jj]); v[4+jj]=f2b(xb[jj]); }
      *(u16x8*)&dstA[(j ^ rsw)<<3] = v;
    }
  }
  __syncthreads();
  f32x4 acc[2][2];
  gemm32(As, WT, col0, acc);
  const int wave = tid>>6, lane = tid&63;
  const int ml = lane&15, quad = lane>>4;
  #pragma unroll
  for (int nf=0;nf<2;nf++){
    int col = col0 + wave*32 + nf*16 + ml;
    float bv = fc1_b[col];
    #pragma unroll
    for (int mf=0;mf<2;mf++)
      #pragma unroll
      for (int r=0;r<4;r++){
        int gr = r0 + mf*16 + quad*4 + r;
        X1[(size_t)gr*512 + col] = acc[mf][nf][r] + bv;
      }
  }
}

// ---------------------------------------------------------------------------
// KA: blocks [0,324) rgcn-GEMM HS = gin@(Wself-INV53*W1)+m3_b;
//     blocks [324,340) Sp = Gsum@[W0|W1] (kk=0: self-computes Gsum from gin);
//     blocks [340,1252) hyperedge aggregation into EB (grid=340 skips edge).
// ---------------------------------------------------------------------------
__global__ __launch_bounds__(256) void ka_kernel(int kk,
    const float* __restrict__ gin, const float* __restrict__ GsIn,
    const ushort_t* __restrict__ WT, const float* __restrict__ m3_b,
    float* __restrict__ HS, float* __restrict__ Sp,
    const float* __restrict__ qmask,
    const float* __restrict__ edge_src, const float* __restrict__ ew_w,
    const int* __restrict__ het, const float* __restrict__ attr1,
    const float* __restrict__ attr2, float* __restrict__ EB)
{
  __shared__ __align__(16) union {
    ushort_t As[32*512];
    struct { float gsum[6][512]; unsigned char spks[54]; } sp;
  } sm;
  const int b = blockIdx.x, tid = threadIdx.x;
  if (b < 324){
    const int r0 = (b>>2)*32, col0 = (b&3)*128;
    {
      int row = tid>>3, seg = tid&7;
      const float* p = gin + (size_t)(r0+row)*512 + seg*64;
      int rsw = row&7;
      ushort_t* dstA = &sm.As[row*512 + seg*64];
      #pragma unroll
      for (int j=0;j<8;j++){
        f32x4 xa = *(const f32x4*)(p+j*8), xb = *(const f32x4*)(p+j*8+4);
        u16x8 v;
        #pragma unroll
        for (int jj=0;jj<4;jj++){ v[jj]=f2b(xa[jj]); v[4+jj]=f2b(xb[jj]); }
        *(u16x8*)&dstA[(j ^ rsw)<<3] = v;
      }
    }
    __syncthreads();
    f32x4 acc[2][2];
    gemm32(sm.As, WT + (size_t)(12+kk)*MATSZ, col0, acc);
    const int wave = tid>>6, lane = tid&63;
    const int ml = lane&15, quad = lane>>4;
    #pragma unroll
    for (int nf=0;nf<2;nf++){
      int col = col0 + wave*32 + nf*16 + ml;
      float bv = m3_b[kk*512 + col];
      #pragma unroll
      for (int mf=0;mf<2;mf++)
        #pragma unroll
        for (int r=0;r<4;r++){
          int gr = r0 + mf*16 + quad*4 + r;
          HS[(size_t)gr*512 + col] = acc[mf][nf][r] + bv;
        }
    }
  } else if (b < 340){
    const int d = b - 324;
    if (kk == 0){
      if (tid < 54)
        sm.sp.spks[tid] = qmask[(tid*16+d)*2+1] > qmask[(tid*16+d)*2];
      __syncthreads();
      int c = tid*2;
      #pragma unroll
      for (int m=0;m<3;m++){
        float a0=0.f,b0v=0.f,a1=0.f,b1v=0.f;
        for (int i=0;i<54;i++){
          float2 x = *(const float2*)&gin[(size_t)(d*162+m*54+i)*512 + c];
          if (sm.sp.spks[i]){ a1+=x.x; b1v+=x.y; } else { a0+=x.x; b0v+=x.y; }
        }
        sm.sp.gsum[m*2][c]   = a0;  sm.sp.gsum[m*2][c+1]   = b0v;
        sm.sp.gsum[m*2+1][c] = a1;  sm.sp.gsum[m*2+1][c+1] = b1v;
      }
    } else {
      const f32x4* g4 = (const f32x4*)(GsIn + (size_t)d*6*512);
      f32x4* l4 = (f32x4*)sm.sp.gsum;
      for (int idx=tid; idx<768; idx+=256) l4[idx] = g4[idx];
    }
    __syncthreads();
    // mini-GEMM (verified sp_stage layout), A from LDS gsum
    const int wave = tid>>6, lane = tid&63;
    const int ml = lane&15, quad = lane>>4;
    const ushort_t* Wb = WT + (size_t)((wave<2 ? 4 : 8)+kk)*MATSZ;
    const int colbase = (wave&1)*256;
    f32x4 sac[16];
    #pragma unroll
    for (int nf=0;nf<16;nf++) sac[nf] = (f32x4){0.f,0.f,0.f,0.f};
    for (int ks=0; ks<16; ks++){
      u16x8 af;
      if (ml < 6){
        const float* gr = &sm.sp.gsum[ml][ks*32 + quad*8];
        f32x4 xa = *(const f32x4*)gr, xb = *(const f32x4*)(gr+4);
        #pragma unroll
        for (int j=0;j<4;j++){ af[j]=f2b(xa[j]); af[4+j]=f2b(xb[j]); }
      } else af = (u16x8){0,0,0,0,0,0,0,0};
      #pragma unroll
      for (int nf=0; nf<16; nf++){
        const ushort_t* wp = Wb + (size_t)(colbase + nf*16 + ml)*512 + ks*32 + quad*8;
        s16x8 bf = *(const s16x8*)wp;
        sac[nf] = __builtin_amdgcn_mfma_f32_16x16x32_bf16((s16x8)af, bf, sac[nf],0,0,0);
      }
    }
    #pragma unroll
    for (int nf=0; nf<16; nf++){
      #pragma unroll
      for (int r=0;r<4;r++){
        int row = quad*4 + r;
        if (row < 6)
          Sp[(size_t)(d*6+row)*1024 + wave*256 + nf*16 + ml] = sac[nf][r];
      }
    }
  } else {
    // hyperedge aggregation (round-1 verified body)
    int e = b - 340;
    int d = e/57, r = e - d*57;
    int col = tid*2;
    float sx=0.f, sy=0.f, de=0.f;
    if (r < 3){
      int nnz0 = d*324 + r*54;
      const float* row = edge_src + ((size_t)(d*162 + r*54))*512 + col;
      for (int i=0;i<54;i++){
        float w = ew_w[nnz0+i];
        float2 x = *(const float2*)row;
        sx += w*x.x; sy += w*x.y; de += w;
        row += 512;
      }
    } else {
      int i = r-3;
      int nnz0 = d*324 + 162 + i*3;
      #pragma unroll
      for (int m=0;m<3;m++){
        float w = ew_w[nnz0+m];
        const float* row = edge_src + ((size_t)(d*162 + m*54 + i))*512 + col;
        float2 x = *(const float2*)row;
        sx += w*x.x; sy += w*x.y; de += w;
      }
    }
    float invde = 1.0f/(de + 1e-8f);
    const float* at = het[e] ? attr1 : attr2;
    float2 o;
    o.x = sx*invde + at[col];
    o.y = sy*invde + at[col+1];
    *(float2*)(EB + (size_t)e*512 + col) = o;
  }
}

// ---------------------------------------------------------------------------
// KB: blocks [0,324) hg-GEMM out = relu(mix(EB)@W + b);
//     blocks [324,420) sf combine (LAST: grid=96, all sf; writes dout+scalar)
// ---------------------------------------------------------------------------
template<bool LAST>
__global__ __launch_bounds__(256) void kb_kernel(int lk,
    const float* __restrict__ EB, const ushort_t* __restrict__ WT,
    const float* __restrict__ hc_b, float* __restrict__ dst,
    const float* __restrict__ gin, const float* __restrict__ HS,
    const float* __restrict__ Sp, const float* __restrict__ qmask,
    const float* __restrict__ he_w,
    float* __restrict__ Gout, float* __restrict__ GsOut,
    const float* __restrict__ OUThg, float* __restrict__ dout,
    float* __restrict__ accp, unsigned int* __restrict__ counter)
{
  __shared__ __align__(16) union {
    ushort_t As[32*512];
    struct { unsigned char spks[54]; float red[256]; } sf;
  } sm;
  const int b = blockIdx.x, tid = threadIdx.x;
  if (!LAST && b < 324){
    const int r0 = (b>>2)*32, col0 = (b&3)*128;
    {
      int row = tid>>3, seg = tid&7, gr = r0+row;
      int d = gr/162, rm = gr-d*162, m = rm/54, i = rm-m*54;
      int em = d*57+m, eu = d*57+3+i;
      float w1 = he_w[em], w2 = he_w[eu], inv = 1.0f/(w1+w2+1e-8f);
      float c1 = w1*inv, c2 = w2*inv;
      const float* pa = EB + (size_t)em*512 + seg*64;
      const float* pb = EB + (size_t)eu*512 + seg*64;
      int rsw = row&7;
      ushort_t* dstA = &sm.As[row*512 + seg*64];
      #pragma unroll
      for (int j=0;j<8;j++){
        f32x4 xa = *(const f32x4*)(pa+j*8), xb = *(const f32x4*)(pa+j*8+4);
        f32x4 ya = *(const f32x4*)(pb+j*8), yb = *(const f32x4*)(pb+j*8+4);
        u16x8 v;
        #pragma unroll
        for (int jj=0;jj<4;jj++){
          v[jj]   = f2b(c1*xa[jj] + c2*ya[jj]);
          v[4+jj] = f2b(c1*xb[jj] + c2*yb[jj]);
        }
        *(u16x8*)&dstA[(j ^ rsw)<<3] = v;
      }
    }
    __syncthreads();
    f32x4 acc[2][2];
    gemm32(sm.As, WT + (size_t)(1+lk)*MATSZ, col0, acc);
    const int wave = tid>>6, lane = tid&63;
    const int ml = lane&15, quad = lane>>4;
    #pragma unroll
    for (int nf=0;nf<2;nf++){
      int col = col0 + wave*32 + nf*16 + ml;
      float bv = hc_b[lk*512 + col];
      #pragma unroll
      for (int mf=0;mf<2;mf++)
        #pragma unroll
        for (int r=0;r<4;r++){
          int gr = r0 + mf*16 + quad*4 + r;
          dst[(size_t)gr*512 + col] = fmaxf(acc[mf][nf][r] + bv, 0.f);
        }
    }
  } else {
    const int sfid = LAST ? b : b-324;
    const int g = sfid>>1, d = g/3;
    const int col = (sfid&1)*256 + tid;
    if (tid < 54)
      sm.sf.spks[tid] = qmask[(tid*16+d)*2+1] > qmask[(tid*16+d)*2];
    __syncthreads();
    const float* r0p = Sp + (size_t)(g*2)*1024;
    const float* r1p = Sp + (size_t)(g*2+1)*1024;
    float S1_0 = r0p[512+col];
    float S1_1 = r1p[512+col];
    float S0_0 = r1p[col];
    float S0_1 = r0p[col];
    size_t base = (size_t)g*54*512 + col;
    float gs0=0.f, gs1=0.f, sumsq=0.f;
    for (int i=0;i<54;i++){
      size_t off = base + (size_t)i*512;
      int sp = sm.sf.spks[i];
      float S1 = sp ? S1_1 : S1_0;
      float S0 = sp ? S0_1 : S0_0;
      float hs = HS[off], gi = gin[off];
      float f = fmaxf((S1 + S0)*INV53 + hs, 0.f);
      float gn = gi + f;
      if (LAST){
        sumsq += f*f;
        dout[off] = OUThg[off] + gn;
      } else {
        Gout[off] = gn;
        if (sp) gs1 += gn; else gs0 += gn;
      }
    }
    if (!LAST){
      GsOut[(size_t)(g*2)*512 + col]   = gs0;
      GsOut[(size_t)(g*2+1)*512 + col] = gs1;
    } else {
      sm.sf.red[tid] = sumsq;
      __syncthreads();
      #pragma unroll
      for (int s=128; s>0; s>>=1){
        if (tid < s) sm.sf.red[tid] += sm.sf.red[tid+s];
        __syncthreads();
      }
      if (tid == 0){
        atomicAdd(accp, sm.sf.red[0]);
        __threadfence();
        unsigned int old = atomicAdd(counter, 1u);
        if (old == 95u)
          dout[(size_t)NNODE*512] = atomicAdd(accp, 0.0f) * (1.0f/1327104.0f);
      }
    }
  }
}

// ---------------------------------------------------------------------------
extern "C" void kernel_launch(void* const* d_in, const int* in_sizes, int n_in,
                              void* d_out, int out_size, void* d_ws, size_t ws_size,
                              hipStream_t stream)
{
  const float* A_in   = (const float*)d_in[0];
  const float* V_in   = (const float*)d_in[1];
  const float* L_in   = (const float*)d_in[2];
  const float* qmask  = (const float*)d_in[3];
  const float* spk    = (const float*)d_in[4];
  const float* fc1_W  = (const float*)d_in[5];
  const float* fc1_b  = (const float*)d_in[6];
  const float* he_w   = (const float*)d_in[7];
  const float* ew_w   = (const float*)d_in[8];
  const float* attr1  = (const float*)d_in[9];
  const float* attr2  = (const float*)d_in[10];
  const float* hc_W   = (const float*)d_in[11];
  const float* hc_b   = (const float*)d_in[12];
  const float* m3_W0  = (const float*)d_in[13];
  const float* m3_W1  = (const float*)d_in[14];
  const float* m3_Ws  = (const float*)d_in[15];
  const float* m3_b   = (const float*)d_in[16];
  const int*   het    = (const int*)d_in[18];
  float* dout = (float*)d_out;

  char* ws = (char*)d_ws;
  ushort_t* WT = (ushort_t*)ws;                       // 16 x 512KB bf16 = 8MB
  float* X1 = (float*)(ws + (size_t)16*MATSZ*2);
  float* OA = X1 + (size_t)NNODE*512;
  float* OB = OA + (size_t)NNODE*512;
  float* OC = OB + (size_t)NNODE*512;
  float* GA = OC + (size_t)NNODE*512;
  float* GB = GA + (size_t)NNODE*512;
  float* HS = GB + (size_t)NNODE*512;
  float* EB = HS + (size_t)NNODE*512;                 // 912*512
  float* Sp = EB + (size_t)912*512;                   // 96*1024
  float* GsA = Sp + 96*1024;                          // 96*512
  float* GsB = GsA + 96*512;
  float* acc = GsB + 96*512;
  unsigned int* counter = (unsigned int*)(acc + 1);

  prep_kernel<<<1024,256,0,stream>>>(fc1_W, hc_W, m3_W0, m3_W1, m3_Ws,
                                     WT, acc, counter);
  fc1_kernel<<<324,256,0,stream>>>(A_in, V_in, L_in, qmask, spk, WT, fc1_b, X1);

  // D1: rgemm0 + Sp0(self-gsum) + edge0
  ka_kernel<<<1252,256,0,stream>>>(0, X1, GsA, WT, m3_b, HS, Sp, qmask,
                                   X1, ew_w, het, attr1, attr2, EB);
  // D2: hg0 + sf0
  kb_kernel<false><<<420,256,0,stream>>>(0, EB, WT, hc_b, OA, X1, HS, Sp,
      qmask, he_w, GA, GsA, nullptr, nullptr, acc, counter);
  // D3
  ka_kernel<<<1252,256,0,stream>>>(1, GA, GsA, WT, m3_b, HS, Sp, qmask,
                                   OA, ew_w, het, attr1, attr2, EB);
  // D4
  kb_kernel<false><<<420,256,0,stream>>>(1, EB, WT, hc_b, OB, GA, HS, Sp,
      qmask, he_w, GB, GsB, nullptr, nullptr, acc, counter);
  // D5
  ka_kernel<<<1252,256,0,stream>>>(2, GB, GsB, WT, m3_b, HS, Sp, qmask,
                                   OB, ew_w, het, attr1, attr2, EB);
  // D6
  kb_kernel<false><<<420,256,0,stream>>>(2, EB, WT, hc_b, OC, GB, HS, Sp,
      qmask, he_w, GA, GsA, nullptr, nullptr, acc, counter);
  // D7: rgemm3 + Sp3 (no edge blocks)
  ka_kernel<<<340,256,0,stream>>>(3, GA, GsA, WT, m3_b, HS, Sp, qmask,
                                  nullptr, ew_w, het, attr1, attr2, EB);
  // D8: sf3 (LAST) -> dout + denoise scalar
  kb_kernel<true><<<96,256,0,stream>>>(3, EB, WT, hc_b, nullptr, GA, HS, Sp,
      qmask, he_w, nullptr, nullptr, OC, dout, acc, counter);

  (void)in_sizes; (void)n_in; (void)out_size; (void)ws_size;
}

// Round 6
// 305.192 us; speedup vs baseline: 1.5285x; 1.5285x over previous
//
#include <hip/hip_runtime.h>

typedef unsigned short ushort_t;
typedef __attribute__((ext_vector_type(4))) float f32x4;
typedef __attribute__((ext_vector_type(8))) short s16x8;
typedef __attribute__((ext_vector_type(8))) unsigned short u16x8;

#define NNODE 2592
#define MATSZ (512*512)
#define INV53 (1.0f/(53.0f + 1e-8f))

__device__ __forceinline__ ushort_t f2b(float f){
  union {unsigned int i; float f;} x; x.f = f;
  unsigned int r = (x.i + 0x7fffu + ((x.i>>16)&1u))>>16;
  return (ushort_t)r;
}

// ---------------------------------------------------------------------------
// gemm32 (verified R5): 32-row x 128-col tile, barrier-free K-loop.
// A in swizzled LDS (32x512 bf16); B streamed global->reg from WT[n][k].
// C/D: row = mf*16 + quad*4 + r, col = wave*32 + nf*16 + ml.
// ---------------------------------------------------------------------------
__device__ __forceinline__ void gemm32(const ushort_t* As,
    const ushort_t* W, int col0, f32x4 acc[2][2])
{
  const int tid = threadIdx.x;
  const int wave = tid>>6, lane = tid&63;
  const int ml = lane&15, quad = lane>>4;
  #pragma unroll
  for (int mf=0;mf<2;mf++)
    #pragma unroll
    for (int nf=0;nf<2;nf++) acc[mf][nf] = (f32x4){0.f,0.f,0.f,0.f};

  const ushort_t* bw0 = W + (size_t)(col0 + wave*32 + ml)*512 + quad*8;
  const ushort_t* bw1 = bw0 + (size_t)16*512;
  const int rsw = ml&7;
  #pragma unroll
  for (int ks=0; ks<16; ks++){
    const int chunk = ks*4 + quad;
    const int abase = (chunk>>3)*64 + (((chunk&7) ^ rsw)<<3);
    s16x8 a0 = *(const s16x8*)&As[(size_t)ml*512 + abase];
    s16x8 a1 = *(const s16x8*)&As[(size_t)(16+ml)*512 + abase];
    s16x8 b0 = *(const s16x8*)(bw0 + ks*32);
    s16x8 b1 = *(const s16x8*)(bw1 + ks*32);
    acc[0][0] = __builtin_amdgcn_mfma_f32_16x16x32_bf16(a0,b0,acc[0][0],0,0,0);
    acc[0][1] = __builtin_amdgcn_mfma_f32_16x16x32_bf16(a0,b1,acc[0][1],0,0,0);
    acc[1][0] = __builtin_amdgcn_mfma_f32_16x16x32_bf16(a1,b0,acc[1][0],0,0,0);
    acc[1][1] = __builtin_amdgcn_mfma_f32_16x16x32_bf16(a1,b1,acc[1][1],0,0,0);
  }
}

// stage 32 contiguous fp32 rows of a [*,512] matrix into swizzled bf16 LDS
__device__ __forceinline__ void stageA_flat(ushort_t* As, const float* src, int r0){
  const int tid = threadIdx.x;
  int row = tid>>3, seg = tid&7;
  const float* p = src + (size_t)(r0+row)*512 + seg*64;
  int rsw = row&7;
  ushort_t* dstA = &As[row*512 + seg*64];
  #pragma unroll
  for (int j=0;j<8;j++){
    f32x4 xa = *(const f32x4*)(p+j*8), xb = *(const f32x4*)(p+j*8+4);
    u16x8 v;
    #pragma unroll
    for (int jj=0;jj<4;jj++){ v[jj]=f2b(xa[jj]); v[4+jj]=f2b(xb[jj]); }
    *(u16x8*)&dstA[(j ^ rsw)<<3] = v;
  }
}

// ---------------------------------------------------------------------------
// prep: blocks [0,1024) transpose fp32 [k][n] -> bf16 WT[w][n][k]
//       (slots 12..15 = Wself - INV53*W1);
//       blocks [1024,1040): FS[d] = per-(m,spk) feature sums (incl spk_emb)
//       + speaker counts.  Block 0 inits acc/counter.
// ---------------------------------------------------------------------------
__global__ __launch_bounds__(256) void prep_kernel(
    const float* __restrict__ fc1, const float* __restrict__ hc,
    const float* __restrict__ m0, const float* __restrict__ m1,
    const float* __restrict__ ms,
    const float* __restrict__ A_in, const float* __restrict__ V_in,
    const float* __restrict__ L_in, const float* __restrict__ qmask,
    const float* __restrict__ spk,
    ushort_t* __restrict__ WT, float* __restrict__ FS,
    float* __restrict__ cnts, float* __restrict__ acc,
    unsigned int* __restrict__ counter)
{
  __shared__ float tile[64][65];
  __shared__ unsigned char spks[54];
  if (blockIdx.x >= 1024){
    int d = blockIdx.x - 1024;
    if (threadIdx.x < 54)
      spks[threadIdx.x] = qmask[(threadIdx.x*16+d)*2+1] > qmask[(threadIdx.x*16+d)*2];
    __syncthreads();
    float cnt1 = 0.f;
    #pragma unroll
    for (int i=0;i<54;i++) cnt1 += (float)spks[i];
    float cnt0 = 54.f - cnt1;
    int col = threadIdx.x*2;
    #pragma unroll
    for (int m=0;m<3;m++){
      float s0x=0.f,s0y=0.f,s1x=0.f,s1y=0.f;
      const float* base = (m==0)?L_in:(m==1)?A_in:V_in;
      for (int i=0;i<54;i++){
        float2 x = *(const float2*)&base[(size_t)(d*54+i)*512 + col];
        if (spks[i]){ s1x+=x.x; s1y+=x.y; } else { s0x+=x.x; s0y+=x.y; }
      }
      if (m==0){
        float2 e0 = *(const float2*)&spk[col];
        float2 e1 = *(const float2*)&spk[512+col];
        s0x += cnt0*e0.x; s0y += cnt0*e0.y;
        s1x += cnt1*e1.x; s1y += cnt1*e1.y;
      }
      float2 o0; o0.x=s0x; o0.y=s0y;
      float2 o1; o1.x=s1x; o1.y=s1y;
      *(float2*)&FS[(size_t)(d*6+m*2  )*512 + col] = o0;
      *(float2*)&FS[(size_t)(d*6+m*2+1)*512 + col] = o1;
    }
    if (threadIdx.x==0){ cnts[d*2]=cnt0; cnts[d*2+1]=cnt1; }
    return;
  }
  if (blockIdx.x==0 && threadIdx.x==0){ *acc = 0.f; *counter = 0u; }
  int w = blockIdx.x>>6, t = blockIdx.x&63, bx = t>>3, by = t&7;
  const float* src = (w==0) ? fc1
                   : (w<4)  ? hc + (size_t)(w-1)*MATSZ
                   : (w<8)  ? m0 + (size_t)(w-4)*MATSZ
                   : (w<12) ? m1 + (size_t)(w-8)*MATSZ
                            : ms + (size_t)(w-12)*MATSZ;
  const float* src2 = (w>=12) ? m1 + (size_t)(w-12)*MATSZ : nullptr;
  ushort_t* dst = WT + (size_t)w*MATSZ;
  int r0 = bx*64, c0 = by*64;
  #pragma unroll
  for (int j=0;j<16;j++){
    int idx = j*256 + threadIdx.x;
    int r = idx>>6, c = idx&63;
    size_t off = (size_t)(r0+r)*512 + c0 + c;
    float v = src[off];
    if (w>=12) v -= INV53 * src2[off];
    tile[r][c] = v;
  }
  __syncthreads();
  #pragma unroll
  for (int j=0;j<16;j++){
    int idx = j*256 + threadIdx.x;
    int r = idx>>6, c = idx&63;
    dst[(size_t)(c0+r)*512 + r0 + c] = f2b(tile[c][r]);
  }
}

// ---------------------------------------------------------------------------
// fc1: blocks [0,324) X1 = feats @ fc1_W + b;
//      blocks [324,336) Gsum0 = FS @ fc1_W + cnt*b   (96x512, 3x4 tiles)
// ---------------------------------------------------------------------------
__global__ __launch_bounds__(256) void fc1_kernel(
    const float* __restrict__ A_in, const float* __restrict__ V_in,
    const float* __restrict__ L_in, const float* __restrict__ qmask,
    const float* __restrict__ spk, const ushort_t* __restrict__ WT,
    const float* __restrict__ fc1_b, float* __restrict__ X1,
    const float* __restrict__ FS, const float* __restrict__ cnts,
    float* __restrict__ Gs)
{
  __shared__ __align__(16) ushort_t As[32*512];
  const int b = blockIdx.x, tid = threadIdx.x;
  const int wave = tid>>6, lane = tid&63;
  const int ml = lane&15, quad = lane>>4;
  if (b < 324){
    const int r0 = (b>>2)*32, col0 = (b&3)*128;
    {
      int row = tid>>3, seg = tid&7, gr = r0+row;
      int d = gr/162, rm = gr-d*162, m = rm/54, i = rm-m*54, t = d*54+i;
      const float* pa = ((m==0)?L_in:(m==1)?A_in:V_in) + (size_t)t*512 + seg*64;
      const float* pb = pa;
      bool hassp = (m==0);
      if (hassp){
        int sp = qmask[(i*16+d)*2+1] > qmask[(i*16+d)*2];
        pb = spk + sp*512 + seg*64;
      }
      int rsw = row&7;
      ushort_t* dstA = &As[row*512 + seg*64];
      #pragma unroll
      for (int j=0;j<8;j++){
        f32x4 xa = *(const f32x4*)(pa+j*8), xb = *(const f32x4*)(pa+j*8+4);
        if (hassp){
          f32x4 ya = *(const f32x4*)(pb+j*8), yb = *(const f32x4*)(pb+j*8+4);
          #pragma unroll
          for (int jj=0;jj<4;jj++){ xa[jj]+=ya[jj]; xb[jj]+=yb[jj]; }
        }
        u16x8 v;
        #pragma unroll
        for (int jj=0;jj<4;jj++){ v[jj]=f2b(xa[jj]); v[4+jj]=f2b(xb[jj]); }
        *(u16x8*)&dstA[(j ^ rsw)<<3] = v;
      }
    }
    __syncthreads();
    f32x4 acc[2][2];
    gemm32(As, WT, col0, acc);
    #pragma unroll
    for (int nf=0;nf<2;nf++){
      int col = col0 + wave*32 + nf*16 + ml;
      float bv = fc1_b[col];
      #pragma unroll
      for (int mf=0;mf<2;mf++)
        #pragma unroll
        for (int r=0;r<4;r++){
          int gr = r0 + mf*16 + quad*4 + r;
          X1[(size_t)gr*512 + col] = acc[mf][nf][r] + bv;
        }
    }
  } else {
    const int bb = b-324;
    const int r0 = (bb>>2)*32, col0 = (bb&3)*128;
    stageA_flat(As, FS, r0);
    __syncthreads();
    f32x4 acc[2][2];
    gemm32(As, WT, col0, acc);
    #pragma unroll
    for (int nf=0;nf<2;nf++){
      int col = col0 + wave*32 + nf*16 + ml;
      float bv = fc1_b[col];
      #pragma unroll
      for (int mf=0;mf<2;mf++)
        #pragma unroll
        for (int r=0;r<4;r++){
          int gr = r0 + mf*16 + quad*4 + r;   // < 96
          float cw = cnts[(gr/6)*2 + (gr&1)];
          Gs[(size_t)gr*512 + col] = acc[mf][nf][r] + cw*bv;
        }
    }
  }
}

// ---------------------------------------------------------------------------
// KA: blocks [0,324)   HS = gin@(Wself-INV53*W1)+m3_b   (gemm32)
//     blocks [324,348) Sp = Gs(96x512) @ [W0|W1]        (gemm32, wide!)
//     blocks [348,1260) hyperedge aggregation into EB
// ---------------------------------------------------------------------------
__global__ __launch_bounds__(256) void ka_kernel(int kk,
    const float* __restrict__ gin, const float* __restrict__ Gs,
    const ushort_t* __restrict__ WT, const float* __restrict__ m3_b,
    float* __restrict__ HS, float* __restrict__ Sp,
    const float* __restrict__ edge_src, const float* __restrict__ ew_w,
    const int* __restrict__ het, const float* __restrict__ attr1,
    const float* __restrict__ attr2, float* __restrict__ EB)
{
  __shared__ __align__(16) ushort_t As[32*512];
  const int b = blockIdx.x, tid = threadIdx.x;
  const int wave = tid>>6, lane = tid&63;
  const int ml = lane&15, quad = lane>>4;
  if (b < 324){
    const int r0 = (b>>2)*32, col0 = (b&3)*128;
    stageA_flat(As, gin, r0);
    __syncthreads();
    f32x4 acc[2][2];
    gemm32(As, WT + (size_t)(12+kk)*MATSZ, col0, acc);
    #pragma unroll
    for (int nf=0;nf<2;nf++){
      int col = col0 + wave*32 + nf*16 + ml;
      float bv = m3_b[kk*512 + col];
      #pragma unroll
      for (int mf=0;mf<2;mf++)
        #pragma unroll
        for (int r=0;r<4;r++){
          int gr = r0 + mf*16 + quad*4 + r;
          HS[(size_t)gr*512 + col] = acc[mf][nf][r] + bv;
        }
    }
  } else if (b < 348){
    const int bb = b-324;
    const int rt = bb>>3, c8 = bb&7;
    const int r0 = rt*32, col0 = (c8&3)*128;
    const ushort_t* W = WT + (size_t)((c8<4 ? 4 : 8)+kk)*MATSZ;
    const int cb = (c8<4) ? 0 : 512;
    stageA_flat(As, Gs, r0);
    __syncthreads();
    f32x4 acc[2][2];
    gemm32(As, W, col0, acc);
    #pragma unroll
    for (int nf=0;nf<2;nf++){
      int col = cb + col0 + wave*32 + nf*16 + ml;
      #pragma unroll
      for (int mf=0;mf<2;mf++)
        #pragma unroll
        for (int r=0;r<4;r++){
          int row = r0 + mf*16 + quad*4 + r;   // < 96
          Sp[(size_t)row*1024 + col] = acc[mf][nf][r];
        }
    }
  } else {
    int e = b - 348;
    int d = e/57, r = e - d*57;
    int col = tid*2;
    float sx=0.f, sy=0.f, de=0.f;
    if (r < 3){
      int nnz0 = d*324 + r*54;
      const float* row = edge_src + ((size_t)(d*162 + r*54))*512 + col;
      for (int i=0;i<54;i++){
        float w = ew_w[nnz0+i];
        float2 x = *(const float2*)row;
        sx += w*x.x; sy += w*x.y; de += w;
        row += 512;
      }
    } else {
      int i = r-3;
      int nnz0 = d*324 + 162 + i*3;
      #pragma unroll
      for (int m=0;m<3;m++){
        float w = ew_w[nnz0+m];
        const float* row = edge_src + ((size_t)(d*162 + m*54 + i))*512 + col;
        float2 x = *(const float2*)row;
        sx += w*x.x; sy += w*x.y; de += w;
      }
    }
    float invde = 1.0f/(de + 1e-8f);
    const float* at = het[e] ? attr1 : attr2;
    float2 o;
    o.x = sx*invde + at[col];
    o.y = sy*invde + at[col+1];
    *(float2*)(EB + (size_t)e*512 + col) = o;
  }
}

// ---------------------------------------------------------------------------
// KB: blocks [0,324) hg-GEMM out = relu(mix(EB)@W + b);
//     blocks [324,420) sf combine (LAST: grid=96, all sf; dout + scalar)
// ---------------------------------------------------------------------------
template<bool LAST>
__global__ __launch_bounds__(256) void kb_kernel(int lk,
    const float* __restrict__ EB, const ushort_t* __restrict__ WT,
    const float* __restrict__ hc_b, float* __restrict__ dst,
    const float* __restrict__ gin, const float* __restrict__ HS,
    const float* __restrict__ Sp, const float* __restrict__ qmask,
    const float* __restrict__ he_w,
    float* __restrict__ Gout, float* __restrict__ GsOut,
    const float* __restrict__ OUThg, float* __restrict__ dout,
    float* __restrict__ accp, unsigned int* __restrict__ counter)
{
  __shared__ __align__(16) union {
    ushort_t As[32*512];
    struct { unsigned char spks[54]; float red[256]; } sf;
  } sm;
  const int b = blockIdx.x, tid = threadIdx.x;
  if (!LAST && b < 324){
    const int r0 = (b>>2)*32, col0 = (b&3)*128;
    {
      int row = tid>>3, seg = tid&7, gr = r0+row;
      int d = gr/162, rm = gr-d*162, m = rm/54, i = rm-m*54;
      int em = d*57+m, eu = d*57+3+i;
      float w1 = he_w[em], w2 = he_w[eu], inv = 1.0f/(w1+w2+1e-8f);
      float c1 = w1*inv, c2 = w2*inv;
      const float* pa = EB + (size_t)em*512 + seg*64;
      const float* pb = EB + (size_t)eu*512 + seg*64;
      int rsw = row&7;
      ushort_t* dstA = &sm.As[row*512 + seg*64];
      #pragma unroll
      for (int j=0;j<8;j++){
        f32x4 xa = *(const f32x4*)(pa+j*8), xb = *(const f32x4*)(pa+j*8+4);
        f32x4 ya = *(const f32x4*)(pb+j*8), yb = *(const f32x4*)(pb+j*8+4);
        u16x8 v;
        #pragma unroll
        for (int jj=0;jj<4;jj++){
          v[jj]   = f2b(c1*xa[jj] + c2*ya[jj]);
          v[4+jj] = f2b(c1*xb[jj] + c2*yb[jj]);
        }
        *(u16x8*)&dstA[(j ^ rsw)<<3] = v;
      }
    }
    __syncthreads();
    f32x4 acc[2][2];
    gemm32(sm.As, WT + (size_t)(1+lk)*MATSZ, col0, acc);
    const int wave = tid>>6, lane = tid&63;
    const int ml = lane&15, quad = lane>>4;
    #pragma unroll
    for (int nf=0;nf<2;nf++){
      int col = col0 + wave*32 + nf*16 + ml;
      float bv = hc_b[lk*512 + col];
      #pragma unroll
      for (int mf=0;mf<2;mf++)
        #pragma unroll
        for (int r=0;r<4;r++){
          int gr = r0 + mf*16 + quad*4 + r;
          dst[(size_t)gr*512 + col] = fmaxf(acc[mf][nf][r] + bv, 0.f);
        }
    }
  } else {
    const int sfid = LAST ? b : b-324;
    const int g = sfid>>1, d = g/3;
    const int col = (sfid&1)*256 + tid;
    if (tid < 54)
      sm.sf.spks[tid] = qmask[(tid*16+d)*2+1] > qmask[(tid*16+d)*2];
    __syncthreads();
    const float* r0p = Sp + (size_t)(g*2)*1024;
    const float* r1p = Sp + (size_t)(g*2+1)*1024;
    float S1_0 = r0p[512+col];
    float S1_1 = r1p[512+col];
    float S0_0 = r1p[col];
    float S0_1 = r0p[col];
    size_t base = (size_t)g*54*512 + col;
    float gs0=0.f, gs1=0.f, sumsq=0.f;
    for (int i=0;i<54;i++){
      size_t off = base + (size_t)i*512;
      int sp = sm.sf.spks[i];
      float S1 = sp ? S1_1 : S1_0;
      float S0 = sp ? S0_1 : S0_0;
      float hs = HS[off], gi = gin[off];
      float f = fmaxf((S1 + S0)*INV53 + hs, 0.f);
      float gn = gi + f;
      if (LAST){
        sumsq += f*f;
        dout[off] = OUThg[off] + gn;
      } else {
        Gout[off] = gn;
        if (sp) gs1 += gn; else gs0 += gn;
      }
    }
    if (!LAST){
      GsOut[(size_t)(g*2)*512 + col]   = gs0;
      GsOut[(size_t)(g*2+1)*512 + col] = gs1;
    } else {
      sm.sf.red[tid] = sumsq;
      __syncthreads();
      #pragma unroll
      for (int s=128; s>0; s>>=1){
        if (tid < s) sm.sf.red[tid] += sm.sf.red[tid+s];
        __syncthreads();
      }
      if (tid == 0){
        atomicAdd(accp, sm.sf.red[0]);
        __threadfence();
        unsigned int old = atomicAdd(counter, 1u);
        if (old == 95u)
          dout[(size_t)NNODE*512] = atomicAdd(accp, 0.0f) * (1.0f/1327104.0f);
      }
    }
  }
}

// ---------------------------------------------------------------------------
extern "C" void kernel_launch(void* const* d_in, const int* in_sizes, int n_in,
                              void* d_out, int out_size, void* d_ws, size_t ws_size,
                              hipStream_t stream)
{
  const float* A_in   = (const float*)d_in[0];
  const float* V_in   = (const float*)d_in[1];
  const float* L_in   = (const float*)d_in[2];
  const float* qmask  = (const float*)d_in[3];
  const float* spk    = (const float*)d_in[4];
  const float* fc1_W  = (const float*)d_in[5];
  const float* fc1_b  = (const float*)d_in[6];
  const float* he_w   = (const float*)d_in[7];
  const float* ew_w   = (const float*)d_in[8];
  const float* attr1  = (const float*)d_in[9];
  const float* attr2  = (const float*)d_in[10];
  const float* hc_W   = (const float*)d_in[11];
  const float* hc_b   = (const float*)d_in[12];
  const float* m3_W0  = (const float*)d_in[13];
  const float* m3_W1  = (const float*)d_in[14];
  const float* m3_Ws  = (const float*)d_in[15];
  const float* m3_b   = (const float*)d_in[16];
  const int*   het    = (const int*)d_in[18];
  float* dout = (float*)d_out;

  char* ws = (char*)d_ws;
  ushort_t* WT = (ushort_t*)ws;                       // 16 x 512KB bf16 = 8MB
  float* X1 = (float*)(ws + (size_t)16*MATSZ*2);
  float* OA = X1 + (size_t)NNODE*512;
  float* OB = OA + (size_t)NNODE*512;
  float* OC = OB + (size_t)NNODE*512;
  float* GA = OC + (size_t)NNODE*512;
  float* GB = GA + (size_t)NNODE*512;
  float* HS = GB + (size_t)NNODE*512;
  float* EB = HS + (size_t)NNODE*512;                 // 912*512
  float* Sp = EB + (size_t)912*512;                   // 96*1024
  float* Gs = Sp + 96*1024;                           // 96*512
  float* FS = Gs + 96*512;                            // 96*512
  float* cnts = FS + 96*512;                          // 32
  float* acc = cnts + 32;
  unsigned int* counter = (unsigned int*)(acc + 1);

  prep_kernel<<<1040,256,0,stream>>>(fc1_W, hc_W, m3_W0, m3_W1, m3_Ws,
                                     A_in, V_in, L_in, qmask, spk,
                                     WT, FS, cnts, acc, counter);
  fc1_kernel<<<336,256,0,stream>>>(A_in, V_in, L_in, qmask, spk, WT, fc1_b,
                                   X1, FS, cnts, Gs);

  // D1: rgemm0 + Sp0 + edge0
  ka_kernel<<<1260,256,0,stream>>>(0, X1, Gs, WT, m3_b, HS, Sp,
                                   X1, ew_w, het, attr1, attr2, EB);
  // D2: hg0 + sf0 (sf emits Gs for next layer)
  kb_kernel<false><<<420,256,0,stream>>>(0, EB, WT, hc_b, OA, X1, HS, Sp,
      qmask, he_w, GA, Gs, nullptr, nullptr, acc, counter);
  // D3
  ka_kernel<<<1260,256,0,stream>>>(1, GA, Gs, WT, m3_b, HS, Sp,
                                   OA, ew_w, het, attr1, attr2, EB);
  // D4
  kb_kernel<false><<<420,256,0,stream>>>(1, EB, WT, hc_b, OB, GA, HS, Sp,
      qmask, he_w, GB, Gs, nullptr, nullptr, acc, counter);
  // D5
  ka_kernel<<<1260,256,0,stream>>>(2, GB, Gs, WT, m3_b, HS, Sp,
                                   OB, ew_w, het, attr1, attr2, EB);
  // D6
  kb_kernel<false><<<420,256,0,stream>>>(2, EB, WT, hc_b, OC, GB, HS, Sp,
      qmask, he_w, GA, Gs, nullptr, nullptr, acc, counter);
  // D7: rgemm3 + Sp3 (no edge blocks)
  ka_kernel<<<348,256,0,stream>>>(3, GA, Gs, WT, m3_b, HS, Sp,
                                  X1, ew_w, het, attr1, attr2, EB);
  // D8: sf3 (LAST) -> dout + denoise scalar
  kb_kernel<true><<<96,256,0,stream>>>(3, EB, WT, hc_b, nullptr, GA, HS, Sp,
      qmask, he_w, nullptr, nullptr, OC, dout, acc, counter);

  (void)in_sizes; (void)n_in; (void)out_size; (void)ws_size;
}

// Round 7
// 260.729 us; speedup vs baseline: 1.7891x; 1.1705x over previous
//
#include <hip/hip_runtime.h>

typedef unsigned short ushort_t;
typedef __attribute__((ext_vector_type(4))) float f32x4;
typedef __attribute__((ext_vector_type(8))) short s16x8;
typedef __attribute__((ext_vector_type(8))) unsigned short u16x8;

#define NNODE 2592
#define MATSZ (512*512)
#define INV53 (1.0f/(53.0f + 1e-8f))

__device__ __forceinline__ ushort_t f2b(float f){
  union {unsigned int i; float f;} x; x.f = f;
  unsigned int r = (x.i + 0x7fffu + ((x.i>>16)&1u))>>16;
  return (ushort_t)r;
}

// ---------------------------------------------------------------------------
// gemm32 (verified R5): 32-row x 128-col tile, barrier-free K-loop.
// A in swizzled LDS (32x512 bf16); B streamed global->reg from WT[n][k].
// C/D: row = mf*16 + quad*4 + r, col = wave*32 + nf*16 + ml.
// ---------------------------------------------------------------------------
__device__ __forceinline__ void gemm32(const ushort_t* As,
    const ushort_t* W, int col0, f32x4 acc[2][2])
{
  const int tid = threadIdx.x;
  const int wave = tid>>6, lane = tid&63;
  const int ml = lane&15, quad = lane>>4;
  #pragma unroll
  for (int mf=0;mf<2;mf++)
    #pragma unroll
    for (int nf=0;nf<2;nf++) acc[mf][nf] = (f32x4){0.f,0.f,0.f,0.f};

  const ushort_t* bw0 = W + (size_t)(col0 + wave*32 + ml)*512 + quad*8;
  const ushort_t* bw1 = bw0 + (size_t)16*512;
  const int rsw = ml&7;
  #pragma unroll
  for (int ks=0; ks<16; ks++){
    const int chunk = ks*4 + quad;
    const int abase = (chunk>>3)*64 + (((chunk&7) ^ rsw)<<3);
    s16x8 a0 = *(const s16x8*)&As[(size_t)ml*512 + abase];
    s16x8 a1 = *(const s16x8*)&As[(size_t)(16+ml)*512 + abase];
    s16x8 b0 = *(const s16x8*)(bw0 + ks*32);
    s16x8 b1 = *(const s16x8*)(bw1 + ks*32);
    acc[0][0] = __builtin_amdgcn_mfma_f32_16x16x32_bf16(a0,b0,acc[0][0],0,0,0);
    acc[0][1] = __builtin_amdgcn_mfma_f32_16x16x32_bf16(a0,b1,acc[0][1],0,0,0);
    acc[1][0] = __builtin_amdgcn_mfma_f32_16x16x32_bf16(a1,b0,acc[1][0],0,0,0);
    acc[1][1] = __builtin_amdgcn_mfma_f32_16x16x32_bf16(a1,b1,acc[1][1],0,0,0);
  }
}

// stage 32 contiguous fp32 rows of a [*,512] matrix into swizzled bf16 LDS
__device__ __forceinline__ void stageA_flat(ushort_t* As, const float* src, int r0){
  const int tid = threadIdx.x;
  int row = tid>>3, seg = tid&7;
  const float* p = src + (size_t)(r0+row)*512 + seg*64;
  int rsw = row&7;
  ushort_t* dstA = &As[row*512 + seg*64];
  #pragma unroll
  for (int j=0;j<8;j++){
    f32x4 xa = *(const f32x4*)(p+j*8), xb = *(const f32x4*)(p+j*8+4);
    u16x8 v;
    #pragma unroll
    for (int jj=0;jj<4;jj++){ v[jj]=f2b(xa[jj]); v[4+jj]=f2b(xb[jj]); }
    *(u16x8*)&dstA[(j ^ rsw)<<3] = v;
  }
}

// ---------------------------------------------------------------------------
// prep: blocks [0,1024) transpose fp32 [k][n] -> bf16 WT[w][n][k]
//       (slots 12..15 = Wself - INV53*W1), VECTORIZED:
//       f32x4 reads -> LDS tile[64][65] -> u16x8 (16B) writes.
//       blocks [1024,1040): FS[d] = per-(m,spk) feature sums (incl spk_emb)
//       + speaker counts.  Block 0 inits acc/counter.
// ---------------------------------------------------------------------------
__global__ __launch_bounds__(256) void prep_kernel(
    const float* __restrict__ fc1, const float* __restrict__ hc,
    const float* __restrict__ m0, const float* __restrict__ m1,
    const float* __restrict__ ms,
    const float* __restrict__ A_in, const float* __restrict__ V_in,
    const float* __restrict__ L_in, const float* __restrict__ qmask,
    const float* __restrict__ spk,
    ushort_t* __restrict__ WT, float* __restrict__ FS,
    float* __restrict__ cnts, float* __restrict__ acc,
    unsigned int* __restrict__ counter)
{
  __shared__ float tile[64][65];
  __shared__ unsigned char spks[54];
  const int tid = threadIdx.x;
  if (blockIdx.x >= 1024){
    int d = blockIdx.x - 1024;
    if (tid < 54)
      spks[tid] = qmask[(tid*16+d)*2+1] > qmask[(tid*16+d)*2];
    __syncthreads();
    float cnt1 = 0.f;
    #pragma unroll
    for (int i=0;i<54;i++) cnt1 += (float)spks[i];
    float cnt0 = 54.f - cnt1;
    int col = tid*2;
    #pragma unroll
    for (int m=0;m<3;m++){
      float s0x=0.f,s0y=0.f,s1x=0.f,s1y=0.f;
      const float* base = (m==0)?L_in:(m==1)?A_in:V_in;
      for (int i=0;i<54;i++){
        float2 x = *(const float2*)&base[(size_t)(d*54+i)*512 + col];
        if (spks[i]){ s1x+=x.x; s1y+=x.y; } else { s0x+=x.x; s0y+=x.y; }
      }
      if (m==0){
        float2 e0 = *(const float2*)&spk[col];
        float2 e1 = *(const float2*)&spk[512+col];
        s0x += cnt0*e0.x; s0y += cnt0*e0.y;
        s1x += cnt1*e1.x; s1y += cnt1*e1.y;
      }
      float2 o0; o0.x=s0x; o0.y=s0y;
      float2 o1; o1.x=s1x; o1.y=s1y;
      *(float2*)&FS[(size_t)(d*6+m*2  )*512 + col] = o0;
      *(float2*)&FS[(size_t)(d*6+m*2+1)*512 + col] = o1;
    }
    if (tid==0){ cnts[d*2]=cnt0; cnts[d*2+1]=cnt1; }
    return;
  }
  if (blockIdx.x==0 && tid==0){ *acc = 0.f; *counter = 0u; }
  int w = blockIdx.x>>6, t = blockIdx.x&63, bx = t>>3, by = t&7;
  const float* src = (w==0) ? fc1
                   : (w<4)  ? hc + (size_t)(w-1)*MATSZ
                   : (w<8)  ? m0 + (size_t)(w-4)*MATSZ
                   : (w<12) ? m1 + (size_t)(w-8)*MATSZ
                            : ms + (size_t)(w-12)*MATSZ;
  const float* src2 = (w>=12) ? m1 + (size_t)(w-12)*MATSZ : nullptr;
  ushort_t* dst = WT + (size_t)w*MATSZ;
  int r0 = bx*64, c0 = by*64;
  // read: f32x4 coalesced; scalar LDS stores (stride-65 -> conflict-free)
  #pragma unroll
  for (int j=0;j<4;j++){
    int idx = j*256 + tid;
    int r = idx>>4, c4 = (idx&15)*4;
    size_t off = (size_t)(r0+r)*512 + c0 + c4;
    f32x4 v = *(const f32x4*)&src[off];
    if (w>=12){
      f32x4 v2 = *(const f32x4*)&src2[off];
      #pragma unroll
      for (int jj=0;jj<4;jj++) v[jj] -= INV53 * v2[jj];
    }
    #pragma unroll
    for (int jj=0;jj<4;jj++) tile[r][c4+jj] = v[jj];
  }
  __syncthreads();
  // write: gather 8 LDS scalars down a column -> one 16B global store
  #pragma unroll
  for (int j=0;j<2;j++){
    int idx = j*256 + tid;
    int c = idx>>3, r8 = (idx&7)*8;
    u16x8 v;
    #pragma unroll
    for (int tt=0;tt<8;tt++) v[tt] = f2b(tile[r8+tt][c]);
    *(u16x8*)&dst[(size_t)(c0+c)*512 + r0 + r8] = v;
  }
}

// ---------------------------------------------------------------------------
// fc1: blocks [0,324) X1 = feats @ fc1_W + b;
//      blocks [324,336) Gsum0 = FS @ fc1_W + cnt*b   (96x512, 3x4 tiles)
// ---------------------------------------------------------------------------
__global__ __launch_bounds__(256) void fc1_kernel(
    const float* __restrict__ A_in, const float* __restrict__ V_in,
    const float* __restrict__ L_in, const float* __restrict__ qmask,
    const float* __restrict__ spk, const ushort_t* __restrict__ WT,
    const float* __restrict__ fc1_b, float* __restrict__ X1,
    const float* __restrict__ FS, const float* __restrict__ cnts,
    float* __restrict__ Gs)
{
  __shared__ __align__(16) ushort_t As[32*512];
  const int b = blockIdx.x, tid = threadIdx.x;
  const int wave = tid>>6, lane = tid&63;
  const int ml = lane&15, quad = lane>>4;
  if (b < 324){
    const int r0 = (b>>2)*32, col0 = (b&3)*128;
    {
      int row = tid>>3, seg = tid&7, gr = r0+row;
      int d = gr/162, rm = gr-d*162, m = rm/54, i = rm-m*54, t = d*54+i;
      const float* pa = ((m==0)?L_in:(m==1)?A_in:V_in) + (size_t)t*512 + seg*64;
      const float* pb = pa;
      bool hassp = (m==0);
      if (hassp){
        int sp = qmask[(i*16+d)*2+1] > qmask[(i*16+d)*2];
        pb = spk + sp*512 + seg*64;
      }
      int rsw = row&7;
      ushort_t* dstA = &As[row*512 + seg*64];
      #pragma unroll
      for (int j=0;j<8;j++){
        f32x4 xa = *(const f32x4*)(pa+j*8), xb = *(const f32x4*)(pa+j*8+4);
        if (hassp){
          f32x4 ya = *(const f32x4*)(pb+j*8), yb = *(const f32x4*)(pb+j*8+4);
          #pragma unroll
          for (int jj=0;jj<4;jj++){ xa[jj]+=ya[jj]; xb[jj]+=yb[jj]; }
        }
        u16x8 v;
        #pragma unroll
        for (int jj=0;jj<4;jj++){ v[jj]=f2b(xa[jj]); v[4+jj]=f2b(xb[jj]); }
        *(u16x8*)&dstA[(j ^ rsw)<<3] = v;
      }
    }
    __syncthreads();
    f32x4 acc[2][2];
    gemm32(As, WT, col0, acc);
    #pragma unroll
    for (int nf=0;nf<2;nf++){
      int col = col0 + wave*32 + nf*16 + ml;
      float bv = fc1_b[col];
      #pragma unroll
      for (int mf=0;mf<2;mf++)
        #pragma unroll
        for (int r=0;r<4;r++){
          int gr = r0 + mf*16 + quad*4 + r;
          X1[(size_t)gr*512 + col] = acc[mf][nf][r] + bv;
        }
    }
  } else {
    const int bb = b-324;
    const int r0 = (bb>>2)*32, col0 = (bb&3)*128;
    stageA_flat(As, FS, r0);
    __syncthreads();
    f32x4 acc[2][2];
    gemm32(As, WT, col0, acc);
    #pragma unroll
    for (int nf=0;nf<2;nf++){
      int col = col0 + wave*32 + nf*16 + ml;
      float bv = fc1_b[col];
      #pragma unroll
      for (int mf=0;mf<2;mf++)
        #pragma unroll
        for (int r=0;r<4;r++){
          int gr = r0 + mf*16 + quad*4 + r;   // < 96
          float cw = cnts[(gr/6)*2 + (gr&1)];
          Gs[(size_t)gr*512 + col] = acc[mf][nf][r] + cw*bv;
        }
    }
  }
}

// ---------------------------------------------------------------------------
// KA: blocks [0,324)   HS = gin@(Wself-INV53*W1)+m3_b   (gemm32)
//     blocks [324,348) Sp = Gs(96x512) @ [W0|W1]        (gemm32, wide)
//     blocks [348,1260) hyperedge aggregation into EB
// ---------------------------------------------------------------------------
__global__ __launch_bounds__(256) void ka_kernel(int kk,
    const float* __restrict__ gin, const float* __restrict__ Gs,
    const ushort_t* __restrict__ WT, const float* __restrict__ m3_b,
    float* __restrict__ HS, float* __restrict__ Sp,
    const float* __restrict__ edge_src, const float* __restrict__ ew_w,
    const int* __restrict__ het, const float* __restrict__ attr1,
    const float* __restrict__ attr2, float* __restrict__ EB)
{
  __shared__ __align__(16) ushort_t As[32*512];
  const int b = blockIdx.x, tid = threadIdx.x;
  const int wave = tid>>6, lane = tid&63;
  const int ml = lane&15, quad = lane>>4;
  if (b < 324){
    const int r0 = (b>>2)*32, col0 = (b&3)*128;
    stageA_flat(As, gin, r0);
    __syncthreads();
    f32x4 acc[2][2];
    gemm32(As, WT + (size_t)(12+kk)*MATSZ, col0, acc);
    #pragma unroll
    for (int nf=0;nf<2;nf++){
      int col = col0 + wave*32 + nf*16 + ml;
      float bv = m3_b[kk*512 + col];
      #pragma unroll
      for (int mf=0;mf<2;mf++)
        #pragma unroll
        for (int r=0;r<4;r++){
          int gr = r0 + mf*16 + quad*4 + r;
          HS[(size_t)gr*512 + col] = acc[mf][nf][r] + bv;
        }
    }
  } else if (b < 348){
    const int bb = b-324;
    const int rt = bb>>3, c8 = bb&7;
    const int r0 = rt*32, col0 = (c8&3)*128;
    const ushort_t* W = WT + (size_t)((c8<4 ? 4 : 8)+kk)*MATSZ;
    const int cb = (c8<4) ? 0 : 512;
    stageA_flat(As, Gs, r0);
    __syncthreads();
    f32x4 acc[2][2];
    gemm32(As, W, col0, acc);
    #pragma unroll
    for (int nf=0;nf<2;nf++){
      int col = cb + col0 + wave*32 + nf*16 + ml;
      #pragma unroll
      for (int mf=0;mf<2;mf++)
        #pragma unroll
        for (int r=0;r<4;r++){
          int row = r0 + mf*16 + quad*4 + r;   // < 96
          Sp[(size_t)row*1024 + col] = acc[mf][nf][r];
        }
    }
  } else {
    int e = b - 348;
    int d = e/57, r = e - d*57;
    int col = tid*2;
    float sx=0.f, sy=0.f, de=0.f;
    if (r < 3){
      int nnz0 = d*324 + r*54;
      const float* row = edge_src + ((size_t)(d*162 + r*54))*512 + col;
      for (int i=0;i<54;i++){
        float w = ew_w[nnz0+i];
        float2 x = *(const float2*)row;
        sx += w*x.x; sy += w*x.y; de += w;
        row += 512;
      }
    } else {
      int i = r-3;
      int nnz0 = d*324 + 162 + i*3;
      #pragma unroll
      for (int m=0;m<3;m++){
        float w = ew_w[nnz0+m];
        const float* row = edge_src + ((size_t)(d*162 + m*54 + i))*512 + col;
        float2 x = *(const float2*)row;
        sx += w*x.x; sy += w*x.y; de += w;
      }
    }
    float invde = 1.0f/(de + 1e-8f);
    const float* at = het[e] ? attr1 : attr2;
    float2 o;
    o.x = sx*invde + at[col];
    o.y = sy*invde + at[col+1];
    *(float2*)(EB + (size_t)e*512 + col) = o;
  }
}

// ---------------------------------------------------------------------------
// KB: blocks [0,324) hg-GEMM out = relu(mix(EB)@W + b);
//     blocks [324,420) sf combine (LAST: grid=96, all sf; dout + scalar)
// ---------------------------------------------------------------------------
template<bool LAST>
__global__ __launch_bounds__(256) void kb_kernel(int lk,
    const float* __restrict__ EB, const ushort_t* __restrict__ WT,
    const float* __restrict__ hc_b, float* __restrict__ dst,
    const float* __restrict__ gin, const float* __restrict__ HS,
    const float* __restrict__ Sp, const float* __restrict__ qmask,
    const float* __restrict__ he_w,
    float* __restrict__ Gout, float* __restrict__ GsOut,
    const float* __restrict__ OUThg, float* __restrict__ dout,
    float* __restrict__ accp, unsigned int* __restrict__ counter)
{
  __shared__ __align__(16) union {
    ushort_t As[32*512];
    struct { unsigned char spks[54]; float red[256]; } sf;
  } sm;
  const int b = blockIdx.x, tid = threadIdx.x;
  if (!LAST && b < 324){
    const int r0 = (b>>2)*32, col0 = (b&3)*128;
    {
      int row = tid>>3, seg = tid&7, gr = r0+row;
      int d = gr/162, rm = gr-d*162, m = rm/54, i = rm-m*54;
      int em = d*57+m, eu = d*57+3+i;
      float w1 = he_w[em], w2 = he_w[eu], inv = 1.0f/(w1+w2+1e-8f);
      float c1 = w1*inv, c2 = w2*inv;
      const float* pa = EB + (size_t)em*512 + seg*64;
      const float* pb = EB + (size_t)eu*512 + seg*64;
      int rsw = row&7;
      ushort_t* dstA = &sm.As[row*512 + seg*64];
      #pragma unroll
      for (int j=0;j<8;j++){
        f32x4 xa = *(const f32x4*)(pa+j*8), xb = *(const f32x4*)(pa+j*8+4);
        f32x4 ya = *(const f32x4*)(pb+j*8), yb = *(const f32x4*)(pb+j*8+4);
        u16x8 v;
        #pragma unroll
        for (int jj=0;jj<4;jj++){
          v[jj]   = f2b(c1*xa[jj] + c2*ya[jj]);
          v[4+jj] = f2b(c1*xb[jj] + c2*yb[jj]);
        }
        *(u16x8*)&dstA[(j ^ rsw)<<3] = v;
      }
    }
    __syncthreads();
    f32x4 acc[2][2];
    gemm32(sm.As, WT + (size_t)(1+lk)*MATSZ, col0, acc);
    const int wave = tid>>6, lane = tid&63;
    const int ml = lane&15, quad = lane>>4;
    #pragma unroll
    for (int nf=0;nf<2;nf++){
      int col = col0 + wave*32 + nf*16 + ml;
      float bv = hc_b[lk*512 + col];
      #pragma unroll
      for (int mf=0;mf<2;mf++)
        #pragma unroll
        for (int r=0;r<4;r++){
          int gr = r0 + mf*16 + quad*4 + r;
          dst[(size_t)gr*512 + col] = fmaxf(acc[mf][nf][r] + bv, 0.f);
        }
    }
  } else {
    const int sfid = LAST ? b : b-324;
    const int g = sfid>>1, d = g/3;
    const int col = (sfid&1)*256 + tid;
    if (tid < 54)
      sm.sf.spks[tid] = qmask[(tid*16+d)*2+1] > qmask[(tid*16+d)*2];
    __syncthreads();
    const float* r0p = Sp + (size_t)(g*2)*1024;
    const float* r1p = Sp + (size_t)(g*2+1)*1024;
    float S1_0 = r0p[512+col];
    float S1_1 = r1p[512+col];
    float S0_0 = r1p[col];
    float S0_1 = r0p[col];
    size_t base = (size_t)g*54*512 + col;
    float gs0=0.f, gs1=0.f, sumsq=0.f;
    for (int i=0;i<54;i++){
      size_t off = base + (size_t)i*512;
      int sp = sm.sf.spks[i];
      float S1 = sp ? S1_1 : S1_0;
      float S0 = sp ? S0_1 : S0_0;
      float hs = HS[off], gi = gin[off];
      float f = fmaxf((S1 + S0)*INV53 + hs, 0.f);
      float gn = gi + f;
      if (LAST){
        sumsq += f*f;
        dout[off] = OUThg[off] + gn;
      } else {
        Gout[off] = gn;
        if (sp) gs1 += gn; else gs0 += gn;
      }
    }
    if (!LAST){
      GsOut[(size_t)(g*2)*512 + col]   = gs0;
      GsOut[(size_t)(g*2+1)*512 + col] = gs1;
    } else {
      sm.sf.red[tid] = sumsq;
      __syncthreads();
      #pragma unroll
      for (int s=128; s>0; s>>=1){
        if (tid < s) sm.sf.red[tid] += sm.sf.red[tid+s];
        __syncthreads();
      }
      if (tid == 0){
        atomicAdd(accp, sm.sf.red[0]);
        __threadfence();
        unsigned int old = atomicAdd(counter, 1u);
        if (old == 95u)
          dout[(size_t)NNODE*512] = atomicAdd(accp, 0.0f) * (1.0f/1327104.0f);
      }
    }
  }
}

// ---------------------------------------------------------------------------
extern "C" void kernel_launch(void* const* d_in, const int* in_sizes, int n_in,
                              void* d_out, int out_size, void* d_ws, size_t ws_size,
                              hipStream_t stream)
{
  const float* A_in   = (const float*)d_in[0];
  const float* V_in   = (const float*)d_in[1];
  const float* L_in   = (const float*)d_in[2];
  const float* qmask  = (const float*)d_in[3];
  const float* spk    = (const float*)d_in[4];
  const float* fc1_W  = (const float*)d_in[5];
  const float* fc1_b  = (const float*)d_in[6];
  const float* he_w   = (const float*)d_in[7];
  const float* ew_w   = (const float*)d_in[8];
  const float* attr1  = (const float*)d_in[9];
  const float* attr2  = (const float*)d_in[10];
  const float* hc_W   = (const float*)d_in[11];
  const float* hc_b   = (const float*)d_in[12];
  const float* m3_W0  = (const float*)d_in[13];
  const float* m3_W1  = (const float*)d_in[14];
  const float* m3_Ws  = (const float*)d_in[15];
  const float* m3_b   = (const float*)d_in[16];
  const int*   het    = (const int*)d_in[18];
  float* dout = (float*)d_out;

  char* ws = (char*)d_ws;
  ushort_t* WT = (ushort_t*)ws;                       // 16 x 512KB bf16 = 8MB
  float* X1 = (float*)(ws + (size_t)16*MATSZ*2);
  float* OA = X1 + (size_t)NNODE*512;
  float* OB = OA + (size_t)NNODE*512;
  float* OC = OB + (size_t)NNODE*512;
  float* GA = OC + (size_t)NNODE*512;
  float* GB = GA + (size_t)NNODE*512;
  float* HS = GB + (size_t)NNODE*512;
  float* EB = HS + (size_t)NNODE*512;                 // 912*512
  float* Sp = EB + (size_t)912*512;                   // 96*1024
  float* Gs = Sp + 96*1024;                           // 96*512
  float* FS = Gs + 96*512;                            // 96*512
  float* cnts = FS + 96*512;                          // 32
  float* acc = cnts + 32;
  unsigned int* counter = (unsigned int*)(acc + 1);

  prep_kernel<<<1040,256,0,stream>>>(fc1_W, hc_W, m3_W0, m3_W1, m3_Ws,
                                     A_in, V_in, L_in, qmask, spk,
                                     WT, FS, cnts, acc, counter);
  fc1_kernel<<<336,256,0,stream>>>(A_in, V_in, L_in, qmask, spk, WT, fc1_b,
                                   X1, FS, cnts, Gs);

  // D1: rgemm0 + Sp0 + edge0
  ka_kernel<<<1260,256,0,stream>>>(0, X1, Gs, WT, m3_b, HS, Sp,
                                   X1, ew_w, het, attr1, attr2, EB);
  // D2: hg0 + sf0 (sf emits Gs for next layer)
  kb_kernel<false><<<420,256,0,stream>>>(0, EB, WT, hc_b, OA, X1, HS, Sp,
      qmask, he_w, GA, Gs, nullptr, nullptr, acc, counter);
  // D3
  ka_kernel<<<1260,256,0,stream>>>(1, GA, Gs, WT, m3_b, HS, Sp,
                                   OA, ew_w, het, attr1, attr2, EB);
  // D4
  kb_kernel<false><<<420,256,0,stream>>>(1, EB, WT, hc_b, OB, GA, HS, Sp,
      qmask, he_w, GB, Gs, nullptr, nullptr, acc, counter);
  // D5
  ka_kernel<<<1260,256,0,stream>>>(2, GB, Gs, WT, m3_b, HS, Sp,
                                   OB, ew_w, het, attr1, attr2, EB);
  // D6
  kb_kernel<false><<<420,256,0,stream>>>(2, EB, WT, hc_b, OC, GB, HS, Sp,
      qmask, he_w, GA, Gs, nullptr, nullptr, acc, counter);
  // D7: rgemm3 + Sp3 (no edge blocks)
  ka_kernel<<<348,256,0,stream>>>(3, GA, Gs, WT, m3_b, HS, Sp,
                                  X1, ew_w, het, attr1, attr2, EB);
  // D8: sf3 (LAST) -> dout + denoise scalar
  kb_kernel<true><<<96,256,0,stream>>>(3, EB, WT, hc_b, nullptr, GA, HS, Sp,
      qmask, he_w, nullptr, nullptr, OC, dout, acc, counter);

  (void)in_sizes; (void)n_in; (void)out_size; (void)ws_size;
}